// Round 1
// 206.002 us; speedup vs baseline: 1.0031x; 1.0031x over previous
//
#include <hip/hip_runtime.h>
#include <hip/hip_bf16.h>

// OTNoiseGate: B=8192, E=8, D=512, P=32, eps=0.05, 50 Sinkhorn iters.
// R7 = R6 (barrier-free waves, direct-global A frags, LDS B tile, 4-deep
// A prefetch) + Sinkhorn-phase overhaul:
//  (a) problem = 8 CONTIGUOUS lanes -> all Sinkhorn reductions are 3 DPP
//      VALU ops (quad_perm x2 + row_half_mirror) instead of 3 serial
//      DS-pipe shuffles (xor 8/16/32) per iteration.
//  (b) Aitken geometric extrapolation to *iteration 50* (not the fixed
//      point): delta += log2(T)-log2(32-T) is a monotone contraction,
//      ratio F' in [0,1). Once the observed update ratio stabilizes
//      (|r-r_prev|<0.002, it>=3, r<0.998) the remaining m steps sum to
//      upd*r*(1-r^m)/(1-r). Matches unconverged 50-iter references too.

#define EXP2F(x) __builtin_amdgcn_exp2f(x)
#define LOG2F(x) __builtin_amdgcn_logf(x)   // v_log_f32 = log2
#define RCPF(x)  __builtin_amdgcn_rcpf(x)

typedef __bf16 bf16x8 __attribute__((ext_vector_type(8)));
typedef float  f32x4  __attribute__((ext_vector_type(4)));

#define BDIM 8192
#define EDIM 8
#define DDIM 512
#define PDIM 32
#define BPB  32             // problems per block (8 per wave x 4 waves)
#define NTHR 256
#define PFD  4              // prefetch depth (chunks in flight per lane)
#define C_SCALE 28.853900817779268f   // log2(e)/eps
#define LOG2E   1.4426950408889634f

// ---- DPP cross-lane helpers: reduce within contiguous 8-lane groups ------
template<int CTRL>
__device__ __forceinline__ float dpp_mov(float x) {
  return __int_as_float(__builtin_amdgcn_update_dpp(
      0, __float_as_int(x), CTRL, 0xF, 0xF, true));
}
__device__ __forceinline__ float dpp_sum8(float x) {
  x += dpp_mov<0xB1>(x);    // quad_perm [1,0,3,2] : lane ^= 1
  x += dpp_mov<0x4E>(x);    // quad_perm [2,3,0,1] : lane ^= 2
  x += dpp_mov<0x141>(x);   // row_half_mirror     : other quad within 8
  return x;
}
__device__ __forceinline__ float dpp_max8(float x) {
  x = fmaxf(x, dpp_mov<0xB1>(x));
  x = fmaxf(x, dpp_mov<0x4E>(x));
  x = fmaxf(x, dpp_mov<0x141>(x));
  return x;
}

__device__ __forceinline__ bf16x8 cvt2(float4 a, float4 b) {
  bf16x8 r;
  r[0] = (__bf16)a.x; r[1] = (__bf16)a.y; r[2] = (__bf16)a.z; r[3] = (__bf16)a.w;
  r[4] = (__bf16)b.x; r[5] = (__bf16)b.y; r[6] = (__bf16)b.z; r[7] = (__bf16)b.w;
  return r;
}

__global__ __launch_bounds__(NTHR, 3)    // 3 blocks/CU, VGPR cap 170
void ot_noise_gate_kernel(const float* __restrict__ tokens,
                          const float* __restrict__ protos,
                          const int*   __restrict__ fullIndexPtr,
                          float*       __restrict__ out) {
  const int fi    = fullIndexPtr[0];
  const int e     = blockIdx.x & (EDIM - 1);   // chunk-major: anchor L3 reuse
  const int b0    = (blockIdx.x >> 3) * BPB;
  float* outVal = out;                         // validity (B,E,1)
  float* outOt  = out + BDIM * EDIM;           // ot_cost  (B,E)

  if (e == fi) {                               // masked slice: constants
    int t = threadIdx.x;
    if (t < BPB) {
      int b = b0 + t;
      outVal[b * EDIM + e] = 1.0f;
      outOt [b * EDIM + e] = 0.0f;
    }
    return;
  }

  __shared__ __align__(16) __bf16 sB[64 * PDIM * 8];  // [oct][p][8] = 32 KiB
  __shared__ float sPNp[8][PDIM];                     // proto-norm partials
  __shared__ __align__(16) float sCw[4][16][36];      // wave-private cost tiles

  const int t  = threadIdx.x;
  const int l  = t & 63;
  const int w  = t >> 6;              // wave 0..3 -> problems b0+8w .. +7
  const int fr = l & 15;              // fragment lane index (M-row / N-col)
  const int q4 = l >> 4;              // k-slice selector (0..3)

  // ---- A-fragment pointer: M-rows 0-7 tokens, 8-15 anchors ------------------
  const int bRow = b0 + 8 * w + (fr & 7);
  const int eSel = (fr < 8) ? e : fi;
  const float4* rp4 = (const float4*)(tokens + ((size_t)bRow * EDIM + eSel) * DDIM);

  // prefetch chunks 0..PFD-1 (in flight during proto staging + barrier drain)
  float4 buf[PFD][2];
  #pragma unroll
  for (int c = 0; c < PFD; ++c) {
    buf[c][0] = rp4[c * 8 + q4 * 2];
    buf[c][1] = rp4[c * 8 + q4 * 2 + 1];
  }

  // ---- stage protos[e] -> bf16 LDS + fp32 norm partials ---------------------
  {
    const float4* pG4 = (const float4*)(protos + (size_t)e * PDIM * DDIM);
    const int p  = t & 31;
    const int oh = t >> 5;            // 0..7
    float pnp = 0.f;
    #pragma unroll
    for (int pass = 0; pass < 8; ++pass) {
      int oct = oh * 8 + pass;        // k = [oct*8, oct*8+8)
      float4 a = pG4[p * 128 + oct * 2];
      float4 b = pG4[p * 128 + oct * 2 + 1];
      pnp += a.x*a.x + a.y*a.y + a.z*a.z + a.w*a.w
           + b.x*b.x + b.y*b.y + b.z*b.z + b.w*b.w;
      *(bf16x8*)&sB[(oct * PDIM + p) * 8] = cvt2(a, b);
    }
    sPNp[oh][p] = pnp;
  }
  __syncthreads();                    // the ONLY barrier

  // ---- K-loop: 4-deep pipelined global A, LDS B, 2 MFMA/chunk ---------------
  f32x4 acc0 = (f32x4){0.f, 0.f, 0.f, 0.f};
  f32x4 acc1 = (f32x4){0.f, 0.f, 0.f, 0.f};
  float ss = 0.f;                     // partial ||row fr||^2 over this lane's k

  #pragma unroll
  for (int kc = 0; kc < 16; ++kc) {
    float4 ca0 = buf[kc % PFD][0];
    float4 ca1 = buf[kc % PFD][1];
    if (kc < 16 - PFD) {              // refill slot; lands PFD chunks ahead
      buf[kc % PFD][0] = rp4[(kc + PFD) * 8 + q4 * 2];
      buf[kc % PFD][1] = rp4[(kc + PFD) * 8 + q4 * 2 + 1];
    }
    ss += ca0.x*ca0.x + ca0.y*ca0.y + ca0.z*ca0.z + ca0.w*ca0.w
        + ca1.x*ca1.x + ca1.y*ca1.y + ca1.z*ca1.z + ca1.w*ca1.w;
    bf16x8 aF  = cvt2(ca0, ca1);
    bf16x8 bF0 = *(const bf16x8*)&sB[((kc * 4 + q4) * PDIM + fr) * 8];
    bf16x8 bF1 = *(const bf16x8*)&sB[((kc * 4 + q4) * PDIM + 16 + fr) * 8];
    acc0 = __builtin_amdgcn_mfma_f32_16x16x32_bf16(aF, bF0, acc0, 0, 0, 0);
    acc1 = __builtin_amdgcn_mfma_f32_16x16x32_bf16(aF, bF1, acc1, 0, 0, 0);
  }

  // ---- norms: reduce the 4 k-slices of each row -----------------------------
  ss += __shfl_xor(ss, 16);
  ss += __shfl_xor(ss, 32);           // lanes (fr,*) now hold ||row fr||^2
  float pn_a = 0.f, pn_b = 0.f;       // proto norms for cols fr, 16+fr
  #pragma unroll
  for (int o = 0; o < 8; ++o) {
    pn_a += sPNp[o][fr];
    pn_b += sPNp[o][16 + fr];
  }

  // ---- epilogue: cost -> wave-private LDS tile ------------------------------
  #pragma unroll
  for (int reg = 0; reg < 4; ++reg) {
    int row = q4 * 4 + reg;           // C/D: row=(l>>4)*4+reg, col=fr
    float nrm = __shfl(ss, row);      // norm of M-row `row`
    sCw[w][row][fr]      = fmaxf(nrm - 2.f * acc0[reg] + pn_a, 0.f);
    sCw[w][row][16 + fr] = fmaxf(nrm - 2.f * acc1[reg] + pn_b, 0.f);
  }
  // DS pipe is in-order per wave: reads below see the writes above.

  // ---- Sinkhorn: problem = 8 CONTIGUOUS lanes, 4 p each ---------------------
  const int i = l >> 3;               // problem 0..7 within wave
  const int s = l & 7;                // p-slice: p in [4s, 4s+4)
  float c0[4], c1[4];
  {
    float4 v0 = *(const float4*)&sCw[w][i][4 * s];       // token costs
    float4 v1 = *(const float4*)&sCw[w][8 + i][4 * s];   // anchor costs
    c0[0] = v0.x; c0[1] = v0.y; c0[2] = v0.z; c0[3] = v0.w;
    c1[0] = v1.x; c1[1] = v1.y; c1[2] = v1.z; c1[3] = v1.w;
  }

  float W[4], dc[4];
  float sum0 = 0.f, mA = -1e30f, mB = -1e30f;
  #pragma unroll
  for (int r = 0; r < 4; ++r) {
    float ka = -c0[r] * C_SCALE, kb = -c1[r] * C_SCALE;
    dc[r] = c1[r] - c0[r];
    sum0 += c0[r];
    mA = fmaxf(mA, ka);
    mB = fmaxf(mB, kb);
  }
  mA = dpp_max8(mA);
  mB = dpp_max8(mB);
  float sa = 0.f, sb = 0.f;
  #pragma unroll
  for (int r = 0; r < 4; ++r) {
    float ka = -c0[r] * C_SCALE, kb = -c1[r] * C_SCALE;
    sa += EXP2F(ka - mA);
    sb += EXP2F(kb - mB);
    W[r] = EXP2F(C_SCALE * dc[r]);    // 2^(k0-k1)
  }
  sa   = dpp_sum8(sa);
  sb   = dpp_sum8(sb);
  sum0 = dpp_sum8(sum0);
  // iteration 1 (reference: lv=0): delta1 = lse2(k1) - lse2(k0)
  float delta = (mB + LOG2F(sb)) - (mA + LOG2F(sa));

  // iterations 2..50: fixed-point w/ geometric extrapolation + fp32 exit.
  // Map F: d -> d + log2(T(d)) - log2(32-T(d)) is a monotone contraction
  // (F' = 1 - sum(x-x^2)*(1/T+1/(32-T)) in [0,1)); once the update ratio
  // r stabilizes, remaining m steps sum to upd*r*(1-r^m)/(1-r) -> jump to
  // the iteration-50 value exactly (also correct when ref is unconverged).
  float updPrev = delta;              // "update" from the d=0 start
  float rPrev   = -1.f;
  bool  live    = true;
  for (int it = 0; it < 49; ++it) {
    float s2 = EXP2F(delta);
    float T = 0.f;
    #pragma unroll
    for (int r = 0; r < 4; ++r)
      T += RCPF(__builtin_fmaf(W[r], s2, 1.0f));   // sigma_p
    T = dpp_sum8(T);                  // in (0,32), uniform over the 8 lanes
    float upd = LOG2F(T) - LOG2F(32.0f - T);
    float rr  = upd * RCPF(updPrev);  // observed contraction ratio
    bool small = fabsf(upd) <= 5e-7f;
    bool geo = live && !small && (it >= 3)
             && (rr > 0.001f) && (rr < 0.998f)
             && (fabsf(rr - rPrev) < 0.002f);
    float mrem = (float)(48 - it);    // fixed-point steps left after this one
    float jump = geo
        ? upd * rr * (1.0f - EXP2F(mrem * LOG2F(rr))) * RCPF(1.0f - rr)
        : 0.0f;
    if (live) delta += upd + jump;
    live = live && !small && !geo;
    rPrev = rr; updPrev = upd;
    if (__ballot(live) == 0ull) break;
  }

  // ---- final transport & outputs -------------------------------------------
  float s2 = EXP2F(delta), sv = 0.f;
  #pragma unroll
  for (int r = 0; r < 4; ++r)
    sv += RCPF(__builtin_fmaf(W[r], s2, 1.0f)) * dc[r];
  sv = dpp_sum8(sv);
  if (s == 0) {
    int b = b0 + 8 * w + i;
    float ot  = (sum0 + sv) * 0.03125f;
    float val = RCPF(1.0f + EXP2F(LOG2E * 6.0f * (ot - 0.25f)));
    outVal[b * EDIM + e] = val;
    outOt [b * EDIM + e] = ot;
  }
}

extern "C" void kernel_launch(void* const* d_in, const int* in_sizes, int n_in,
                              void* d_out, int out_size, void* d_ws, size_t ws_size,
                              hipStream_t stream) {
  const float* tokens = (const float*)d_in[0];   // (8192, 8, 512) fp32
  const float* protos = (const float*)d_in[1];   // (8, 32, 512) fp32
  const int*   fidx   = (const int*)d_in[2];     // scalar
  float* out = (float*)d_out;                    // 65536 validity + 65536 ot

  dim3 grid((BDIM / BPB) * EDIM);                // 2048 blocks, chunk-major
  ot_noise_gate_kernel<<<grid, NTHR, 0, stream>>>(tokens, protos, fidx, out);
}

// Round 2
// 196.544 us; speedup vs baseline: 1.0513x; 1.0481x over previous
//
#include <hip/hip_runtime.h>
#include <hip/hip_bf16.h>

// OTNoiseGate: B=8192, E=8, D=512, P=32, eps=0.05, 50 Sinkhorn iters.
// R8 = R7 (DPP Sinkhorn, geometric extrapolation) + memory-phase overhaul:
//  (a) prep kernel pre-packs protos -> bf16 in the LDS slot layout
//      [e][oct][p][8] in d_ws + per-(e,p) norms; main kernel stages via
//      global_load_lds width=16 (no VGPR roundtrip, no cvt VALU, half the
//      staging bytes: 32 KB/block instead of 64 KB fp32).
//  (b) A-prefetch depth 4 -> 6: lead ~990 cy >= ~900 cy HBM latency, so
//      the K-loop steady state no longer eats residual global-load stall.

#define EXP2F(x) __builtin_amdgcn_exp2f(x)
#define LOG2F(x) __builtin_amdgcn_logf(x)   // v_log_f32 = log2
#define RCPF(x)  __builtin_amdgcn_rcpf(x)

typedef __bf16 bf16x8 __attribute__((ext_vector_type(8)));
typedef float  f32x4  __attribute__((ext_vector_type(4)));

#define BDIM 8192
#define EDIM 8
#define DDIM 512
#define PDIM 32
#define BPB  32             // problems per block (8 per wave x 4 waves)
#define NTHR 256
#define PFD  6              // prefetch depth (chunks in flight per lane)
#define C_SCALE 28.853900817779268f   // log2(e)/eps
#define LOG2E   1.4426950408889634f

#define GLOBAL_AS __attribute__((address_space(1)))
#define LDS_AS    __attribute__((address_space(3)))

__device__ __forceinline__ void gload_lds16(const void* g, void* l) {
  // dest: wave-uniform base + lane*16 (hardware-defined); src: per-lane addr
  __builtin_amdgcn_global_load_lds((GLOBAL_AS const void*)g,
                                   (LDS_AS void*)l, 16, 0, 0);
}

// ---- DPP cross-lane helpers: reduce within contiguous 8-lane groups ------
template<int CTRL>
__device__ __forceinline__ float dpp_mov(float x) {
  return __int_as_float(__builtin_amdgcn_update_dpp(
      0, __float_as_int(x), CTRL, 0xF, 0xF, true));
}
__device__ __forceinline__ float dpp_sum8(float x) {
  x += dpp_mov<0xB1>(x);    // quad_perm [1,0,3,2] : lane ^= 1
  x += dpp_mov<0x4E>(x);    // quad_perm [2,3,0,1] : lane ^= 2
  x += dpp_mov<0x141>(x);   // row_half_mirror     : other quad within 8
  return x;
}
__device__ __forceinline__ float dpp_max8(float x) {
  x = fmaxf(x, dpp_mov<0xB1>(x));
  x = fmaxf(x, dpp_mov<0x4E>(x));
  x = fmaxf(x, dpp_mov<0x141>(x));
  return x;
}

__device__ __forceinline__ bf16x8 cvt2(float4 a, float4 b) {
  bf16x8 r;
  r[0] = (__bf16)a.x; r[1] = (__bf16)a.y; r[2] = (__bf16)a.z; r[3] = (__bf16)a.w;
  r[4] = (__bf16)b.x; r[5] = (__bf16)b.y; r[6] = (__bf16)b.z; r[7] = (__bf16)b.w;
  return r;
}

// ---- prep: protos fp32 -> bf16 [e][oct][p][8] + norms[e*32+p] ------------
// 16384 threads; wave = one (e,p), lane = oct (64 octs of 8 elems = 512).
__global__ __launch_bounds__(256)
void prep_protos_kernel(const float* __restrict__ protos,
                        __bf16* __restrict__ pbf,
                        float*  __restrict__ pnorm) {
  const int idx = blockIdx.x * 256 + threadIdx.x;   // 0..16383
  const int oct = idx & 63;
  const int ep  = idx >> 6;                          // e*32 + p
  const int p   = ep & 31;
  const int e   = ep >> 5;
  const float4* src = (const float4*)(protos + (size_t)ep * DDIM) + oct * 2;
  float4 a = src[0], b = src[1];
  float pnp = a.x*a.x + a.y*a.y + a.z*a.z + a.w*a.w
            + b.x*b.x + b.y*b.y + b.z*b.z + b.w*b.w;
  *(bf16x8*)&pbf[((size_t)e * 2048 + oct * 32 + p) * 8] = cvt2(a, b);
  #pragma unroll
  for (int d = 1; d < 64; d <<= 1) pnp += __shfl_xor(pnp, d);
  if (oct == 0) pnorm[ep] = pnp;
}

__global__ __launch_bounds__(NTHR, 3)    // 3 blocks/CU, VGPR cap 170
void ot_noise_gate_kernel(const float* __restrict__ tokens,
                          const __bf16* __restrict__ pbf,
                          const float*  __restrict__ pnorm,
                          const int*   __restrict__ fullIndexPtr,
                          float*       __restrict__ out) {
  const int fi    = fullIndexPtr[0];
  const int e     = blockIdx.x & (EDIM - 1);   // chunk-major: anchor L3 reuse
  const int b0    = (blockIdx.x >> 3) * BPB;
  float* outVal = out;                         // validity (B,E,1)
  float* outOt  = out + BDIM * EDIM;           // ot_cost  (B,E)

  if (e == fi) {                               // masked slice: constants
    int t = threadIdx.x;
    if (t < BPB) {
      int b = b0 + t;
      outVal[b * EDIM + e] = 1.0f;
      outOt [b * EDIM + e] = 0.0f;
    }
    return;
  }

  __shared__ __align__(16) __bf16 sB[64 * PDIM * 8];  // [oct][p][8] = 32 KiB
  __shared__ __align__(16) float sCw[4][16][36];      // wave-private cost tiles

  const int t  = threadIdx.x;
  const int l  = t & 63;
  const int w  = t >> 6;              // wave 0..3 -> problems b0+8w .. +7
  const int fr = l & 15;              // fragment lane index (M-row / N-col)
  const int q4 = l >> 4;              // k-slice selector (0..3)

  // ---- A-fragment pointer: M-rows 0-7 tokens, 8-15 anchors ------------------
  const int bRow = b0 + 8 * w + (fr & 7);
  const int eSel = (fr < 8) ? e : fi;
  const float4* rp4 = (const float4*)(tokens + ((size_t)bRow * EDIM + eSel) * DDIM);

  // prefetch chunks 0..PFD-1 (in flight during proto staging + barrier drain)
  float4 buf[PFD][2];
  #pragma unroll
  for (int c = 0; c < PFD; ++c) {
    buf[c][0] = rp4[c * 8 + q4 * 2];
    buf[c][1] = rp4[c * 8 + q4 * 2 + 1];
  }

  // ---- stage protos[e] (pre-packed bf16) -> LDS via global_load_lds ---------
  // slots f = oct*32+p (16 B each); wave w covers f in [w*512, w*512+512),
  // 8 insts x 64 lanes x 16 B; dest is linear: base + lane*16.
  {
    const __bf16* pbfE = pbf + (size_t)e * 2048 * 8;
    #pragma unroll
    for (int j = 0; j < 8; ++j) {
      int f0 = w * 512 + j * 64;
      gload_lds16(pbfE + (size_t)(f0 + l) * 8, &sB[(size_t)f0 * 8]);
    }
  }
  // proto norms for this lane's two columns (tiny, L2/L3-hot)
  float pn_a = pnorm[e * PDIM + fr];
  float pn_b = pnorm[e * PDIM + 16 + fr];
  __syncthreads();                    // the ONLY barrier (drains vmcnt)

  // ---- K-loop: 6-deep pipelined global A, LDS B, 2 MFMA/chunk ---------------
  f32x4 acc0 = (f32x4){0.f, 0.f, 0.f, 0.f};
  f32x4 acc1 = (f32x4){0.f, 0.f, 0.f, 0.f};
  float ss = 0.f;                     // partial ||row fr||^2 over this lane's k

  #pragma unroll
  for (int kc = 0; kc < 16; ++kc) {
    float4 ca0 = buf[kc % PFD][0];
    float4 ca1 = buf[kc % PFD][1];
    if (kc < 16 - PFD) {              // refill slot; lands PFD chunks ahead
      buf[kc % PFD][0] = rp4[(kc + PFD) * 8 + q4 * 2];
      buf[kc % PFD][1] = rp4[(kc + PFD) * 8 + q4 * 2 + 1];
    }
    ss += ca0.x*ca0.x + ca0.y*ca0.y + ca0.z*ca0.z + ca0.w*ca0.w
        + ca1.x*ca1.x + ca1.y*ca1.y + ca1.z*ca1.z + ca1.w*ca1.w;
    bf16x8 aF  = cvt2(ca0, ca1);
    bf16x8 bF0 = *(const bf16x8*)&sB[((kc * 4 + q4) * PDIM + fr) * 8];
    bf16x8 bF1 = *(const bf16x8*)&sB[((kc * 4 + q4) * PDIM + 16 + fr) * 8];
    acc0 = __builtin_amdgcn_mfma_f32_16x16x32_bf16(aF, bF0, acc0, 0, 0, 0);
    acc1 = __builtin_amdgcn_mfma_f32_16x16x32_bf16(aF, bF1, acc1, 0, 0, 0);
  }

  // ---- norms: reduce the 4 k-slices of each row -----------------------------
  ss += __shfl_xor(ss, 16);
  ss += __shfl_xor(ss, 32);           // lanes (fr,*) now hold ||row fr||^2

  // ---- epilogue: cost -> wave-private LDS tile ------------------------------
  #pragma unroll
  for (int reg = 0; reg < 4; ++reg) {
    int row = q4 * 4 + reg;           // C/D: row=(l>>4)*4+reg, col=fr
    float nrm = __shfl(ss, row);      // norm of M-row `row`
    sCw[w][row][fr]      = fmaxf(nrm - 2.f * acc0[reg] + pn_a, 0.f);
    sCw[w][row][16 + fr] = fmaxf(nrm - 2.f * acc1[reg] + pn_b, 0.f);
  }
  // DS pipe is in-order per wave: reads below see the writes above.

  // ---- Sinkhorn: problem = 8 CONTIGUOUS lanes, 4 p each ---------------------
  const int i = l >> 3;               // problem 0..7 within wave
  const int s = l & 7;                // p-slice: p in [4s, 4s+4)
  float c0[4], c1[4];
  {
    float4 v0 = *(const float4*)&sCw[w][i][4 * s];       // token costs
    float4 v1 = *(const float4*)&sCw[w][8 + i][4 * s];   // anchor costs
    c0[0] = v0.x; c0[1] = v0.y; c0[2] = v0.z; c0[3] = v0.w;
    c1[0] = v1.x; c1[1] = v1.y; c1[2] = v1.z; c1[3] = v1.w;
  }

  float W[4], dc[4];
  float sum0 = 0.f, mA = -1e30f, mB = -1e30f;
  #pragma unroll
  for (int r = 0; r < 4; ++r) {
    float ka = -c0[r] * C_SCALE, kb = -c1[r] * C_SCALE;
    dc[r] = c1[r] - c0[r];
    sum0 += c0[r];
    mA = fmaxf(mA, ka);
    mB = fmaxf(mB, kb);
  }
  mA = dpp_max8(mA);
  mB = dpp_max8(mB);
  float sa = 0.f, sb = 0.f;
  #pragma unroll
  for (int r = 0; r < 4; ++r) {
    float ka = -c0[r] * C_SCALE, kb = -c1[r] * C_SCALE;
    sa += EXP2F(ka - mA);
    sb += EXP2F(kb - mB);
    W[r] = EXP2F(C_SCALE * dc[r]);    // 2^(k0-k1)
  }
  sa   = dpp_sum8(sa);
  sb   = dpp_sum8(sb);
  sum0 = dpp_sum8(sum0);
  // iteration 1 (reference: lv=0): delta1 = lse2(k1) - lse2(k0)
  float delta = (mB + LOG2F(sb)) - (mA + LOG2F(sa));

  // iterations 2..50: fixed-point w/ geometric extrapolation + fp32 exit.
  float updPrev = delta;              // "update" from the d=0 start
  float rPrev   = -1.f;
  bool  live    = true;
  for (int it = 0; it < 49; ++it) {
    float s2 = EXP2F(delta);
    float T = 0.f;
    #pragma unroll
    for (int r = 0; r < 4; ++r)
      T += RCPF(__builtin_fmaf(W[r], s2, 1.0f));   // sigma_p
    T = dpp_sum8(T);                  // in (0,32), uniform over the 8 lanes
    float upd = LOG2F(T) - LOG2F(32.0f - T);
    float rr  = upd * RCPF(updPrev);  // observed contraction ratio
    bool small = fabsf(upd) <= 5e-7f;
    bool geo = live && !small && (it >= 3)
             && (rr > 0.001f) && (rr < 0.998f)
             && (fabsf(rr - rPrev) < 0.002f);
    float mrem = (float)(48 - it);    // fixed-point steps left after this one
    float jump = geo
        ? upd * rr * (1.0f - EXP2F(mrem * LOG2F(rr))) * RCPF(1.0f - rr)
        : 0.0f;
    if (live) delta += upd + jump;
    live = live && !small && !geo;
    rPrev = rr; updPrev = upd;
    if (__ballot(live) == 0ull) break;
  }

  // ---- final transport & outputs -------------------------------------------
  float s2 = EXP2F(delta), sv = 0.f;
  #pragma unroll
  for (int r = 0; r < 4; ++r)
    sv += RCPF(__builtin_fmaf(W[r], s2, 1.0f)) * dc[r];
  sv = dpp_sum8(sv);
  if (s == 0) {
    int b = b0 + 8 * w + i;
    float ot  = (sum0 + sv) * 0.03125f;
    float val = RCPF(1.0f + EXP2F(LOG2E * 6.0f * (ot - 0.25f)));
    outVal[b * EDIM + e] = val;
    outOt [b * EDIM + e] = ot;
  }
}

extern "C" void kernel_launch(void* const* d_in, const int* in_sizes, int n_in,
                              void* d_out, int out_size, void* d_ws, size_t ws_size,
                              hipStream_t stream) {
  const float* tokens = (const float*)d_in[0];   // (8192, 8, 512) fp32
  const float* protos = (const float*)d_in[1];   // (8, 32, 512) fp32
  const int*   fidx   = (const int*)d_in[2];     // scalar
  float* out = (float*)d_out;                    // 65536 validity + 65536 ot

  __bf16* pbf   = (__bf16*)d_ws;                          // 256 KiB
  float*  pnorm = (float*)((char*)d_ws + 256 * 1024);     // 1 KiB

  prep_protos_kernel<<<64, 256, 0, stream>>>(protos, pbf, pnorm);
  dim3 grid((BDIM / BPB) * EDIM);                // 2048 blocks, chunk-major
  ot_noise_gate_kernel<<<grid, NTHR, 0, stream>>>(tokens, pbf, pnorm, fidx, out);
}

// Round 3
// 194.499 us; speedup vs baseline: 1.0624x; 1.0105x over previous
//
#include <hip/hip_runtime.h>
#include <hip/hip_bf16.h>

// OTNoiseGate: B=8192, E=8, D=512, P=32, eps=0.05, 50 Sinkhorn iters.
// R9 = R8 (prep-packed bf16 protos + global_load_lds staging, PFD=6,
// DPP Sinkhorn w/ geometric extrapolation) + XCD load-balance fix:
//  - OLD mapping had e = blockIdx&7 and XCD = blockIdx%8  =>  XCD == e,
//    so ALL 256 instant-exit (e==fi) blocks landed on one XCD: 32 CUs
//    idle for the whole kernel (x8/7 time). Now the grid is 1792 working
//    blocks only; fi constant-writes moved into the prep kernel.
//  - New mapping: xcd = blk&7 selects chunk low bits, eIdx = (blk>>3)%7
//    cycles e within an XCD -> perfect 224-blocks/XCD balance AND the 7
//    same-chunk blocks (sharing anchor rows) are dispatch-adjacent on the
//    SAME XCD -> anchors hit local L2 instead of L3.

#define EXP2F(x) __builtin_amdgcn_exp2f(x)
#define LOG2F(x) __builtin_amdgcn_logf(x)   // v_log_f32 = log2
#define RCPF(x)  __builtin_amdgcn_rcpf(x)

typedef __bf16 bf16x8 __attribute__((ext_vector_type(8)));
typedef float  f32x4  __attribute__((ext_vector_type(4)));

#define BDIM 8192
#define EDIM 8
#define DDIM 512
#define PDIM 32
#define BPB  32             // problems per block (8 per wave x 4 waves)
#define NTHR 256
#define PFD  6              // prefetch depth (chunks in flight per lane)
#define C_SCALE 28.853900817779268f   // log2(e)/eps
#define LOG2E   1.4426950408889634f

#define GLOBAL_AS __attribute__((address_space(1)))
#define LDS_AS    __attribute__((address_space(3)))

__device__ __forceinline__ void gload_lds16(const void* g, void* l) {
  // dest: wave-uniform base + lane*16 (hardware-defined); src: per-lane addr
  __builtin_amdgcn_global_load_lds((GLOBAL_AS const void*)g,
                                   (LDS_AS void*)l, 16, 0, 0);
}

// ---- DPP cross-lane helpers: reduce within contiguous 8-lane groups ------
template<int CTRL>
__device__ __forceinline__ float dpp_mov(float x) {
  return __int_as_float(__builtin_amdgcn_update_dpp(
      0, __float_as_int(x), CTRL, 0xF, 0xF, true));
}
__device__ __forceinline__ float dpp_sum8(float x) {
  x += dpp_mov<0xB1>(x);    // quad_perm [1,0,3,2] : lane ^= 1
  x += dpp_mov<0x4E>(x);    // quad_perm [2,3,0,1] : lane ^= 2
  x += dpp_mov<0x141>(x);   // row_half_mirror     : other quad within 8
  return x;
}
__device__ __forceinline__ float dpp_max8(float x) {
  x = fmaxf(x, dpp_mov<0xB1>(x));
  x = fmaxf(x, dpp_mov<0x4E>(x));
  x = fmaxf(x, dpp_mov<0x141>(x));
  return x;
}

__device__ __forceinline__ bf16x8 cvt2(float4 a, float4 b) {
  bf16x8 r;
  r[0] = (__bf16)a.x; r[1] = (__bf16)a.y; r[2] = (__bf16)a.z; r[3] = (__bf16)a.w;
  r[4] = (__bf16)b.x; r[5] = (__bf16)b.y; r[6] = (__bf16)b.z; r[7] = (__bf16)b.w;
  return r;
}

// ---- prep: protos fp32 -> bf16 [e][oct][p][8] + norms[e*32+p],
//      and the masked-slice (e==fi) constant outputs.
// 16384 threads; wave = one (e,p), lane = oct (64 octs of 8 elems = 512).
__global__ __launch_bounds__(256)
void prep_protos_kernel(const float* __restrict__ protos,
                        const int*   __restrict__ fullIndexPtr,
                        __bf16* __restrict__ pbf,
                        float*  __restrict__ pnorm,
                        float*  __restrict__ out) {
  const int idx = blockIdx.x * 256 + threadIdx.x;   // 0..16383
  const int oct = idx & 63;
  const int ep  = idx >> 6;                          // e*32 + p
  const float4* src = (const float4*)(protos + (size_t)ep * DDIM) + oct * 2;
  float4 a = src[0], b = src[1];
  float pnp = a.x*a.x + a.y*a.y + a.z*a.z + a.w*a.w
            + b.x*b.x + b.y*b.y + b.z*b.z + b.w*b.w;
  const int e = ep >> 5;
  *(bf16x8*)&pbf[((size_t)e * 2048 + oct * 32 + (ep & 31)) * 8] = cvt2(a, b);
  #pragma unroll
  for (int d = 1; d < 64; d <<= 1) pnp += __shfl_xor(pnp, d);
  if (oct == 0) pnorm[ep] = pnp;

  // masked slice (e==fi): validity=1, ot=0 for all b
  const int fi = fullIndexPtr[0];
  if (idx < BDIM) {
    out[(size_t)idx * EDIM + fi] = 1.0f;                     // validity
    out[(size_t)BDIM * EDIM + (size_t)idx * EDIM + fi] = 0.0f; // ot_cost
  }
}

__global__ __launch_bounds__(NTHR, 3)    // 3 blocks/CU, VGPR cap 170
void ot_noise_gate_kernel(const float* __restrict__ tokens,
                          const __bf16* __restrict__ pbf,
                          const float*  __restrict__ pnorm,
                          const int*   __restrict__ fullIndexPtr,
                          float*       __restrict__ out) {
  const int fi = fullIndexPtr[0];
  // XCD-balanced decomposition: 1792 working blocks.
  const int u    = blockIdx.x;
  const int xcd  = u & 7;            // HW: XCD = blockIdx % 8 (round-robin)
  const int r    = u >> 3;           // 0..223
  const int cHi  = r / 7;            // 0..31
  const int eIdx = r - cHi * 7;      // 0..6
  const int chunk = cHi * 8 + xcd;   // same-chunk blocks share an XCD
  const int e    = eIdx + (eIdx >= fi ? 1 : 0);   // skip the masked slice
  const int b0   = chunk * BPB;
  float* outVal = out;                         // validity (B,E,1)
  float* outOt  = out + BDIM * EDIM;           // ot_cost  (B,E)

  __shared__ __align__(16) __bf16 sB[64 * PDIM * 8];  // [oct][p][8] = 32 KiB
  __shared__ __align__(16) float sCw[4][16][36];      // wave-private cost tiles

  const int t  = threadIdx.x;
  const int l  = t & 63;
  const int w  = t >> 6;              // wave 0..3 -> problems b0+8w .. +7
  const int fr = l & 15;              // fragment lane index (M-row / N-col)
  const int q4 = l >> 4;              // k-slice selector (0..3)

  // ---- A-fragment pointer: M-rows 0-7 tokens, 8-15 anchors ------------------
  const int bRow = b0 + 8 * w + (fr & 7);
  const int eSel = (fr < 8) ? e : fi;
  const float4* rp4 = (const float4*)(tokens + ((size_t)bRow * EDIM + eSel) * DDIM);

  // prefetch chunks 0..PFD-1 (in flight during proto staging + barrier drain)
  float4 buf[PFD][2];
  #pragma unroll
  for (int c = 0; c < PFD; ++c) {
    buf[c][0] = rp4[c * 8 + q4 * 2];
    buf[c][1] = rp4[c * 8 + q4 * 2 + 1];
  }

  // ---- stage protos[e] (pre-packed bf16) -> LDS via global_load_lds ---------
  // slots f = oct*32+p (16 B each); wave w covers f in [w*512, w*512+512),
  // 8 insts x 64 lanes x 16 B; dest is linear: base + lane*16.
  {
    const __bf16* pbfE = pbf + (size_t)e * 2048 * 8;
    #pragma unroll
    for (int j = 0; j < 8; ++j) {
      int f0 = w * 512 + j * 64;
      gload_lds16(pbfE + (size_t)(f0 + l) * 8, &sB[(size_t)f0 * 8]);
    }
  }
  // proto norms for this lane's two columns (tiny, L2-hot)
  float pn_a = pnorm[e * PDIM + fr];
  float pn_b = pnorm[e * PDIM + 16 + fr];
  __syncthreads();                    // the ONLY barrier (drains vmcnt)

  // ---- K-loop: 6-deep pipelined global A, LDS B, 2 MFMA/chunk ---------------
  f32x4 acc0 = (f32x4){0.f, 0.f, 0.f, 0.f};
  f32x4 acc1 = (f32x4){0.f, 0.f, 0.f, 0.f};
  float ss = 0.f;                     // partial ||row fr||^2 over this lane's k

  #pragma unroll
  for (int kc = 0; kc < 16; ++kc) {
    float4 ca0 = buf[kc % PFD][0];
    float4 ca1 = buf[kc % PFD][1];
    if (kc < 16 - PFD) {              // refill slot; lands PFD chunks ahead
      buf[kc % PFD][0] = rp4[(kc + PFD) * 8 + q4 * 2];
      buf[kc % PFD][1] = rp4[(kc + PFD) * 8 + q4 * 2 + 1];
    }
    ss += ca0.x*ca0.x + ca0.y*ca0.y + ca0.z*ca0.z + ca0.w*ca0.w
        + ca1.x*ca1.x + ca1.y*ca1.y + ca1.z*ca1.z + ca1.w*ca1.w;
    bf16x8 aF  = cvt2(ca0, ca1);
    bf16x8 bF0 = *(const bf16x8*)&sB[((kc * 4 + q4) * PDIM + fr) * 8];
    bf16x8 bF1 = *(const bf16x8*)&sB[((kc * 4 + q4) * PDIM + 16 + fr) * 8];
    acc0 = __builtin_amdgcn_mfma_f32_16x16x32_bf16(aF, bF0, acc0, 0, 0, 0);
    acc1 = __builtin_amdgcn_mfma_f32_16x16x32_bf16(aF, bF1, acc1, 0, 0, 0);
  }

  // ---- norms: reduce the 4 k-slices of each row -----------------------------
  ss += __shfl_xor(ss, 16);
  ss += __shfl_xor(ss, 32);           // lanes (fr,*) now hold ||row fr||^2

  // ---- epilogue: cost -> wave-private LDS tile ------------------------------
  #pragma unroll
  for (int reg = 0; reg < 4; ++reg) {
    int row = q4 * 4 + reg;           // C/D: row=(l>>4)*4+reg, col=fr
    float nrm = __shfl(ss, row);      // norm of M-row `row`
    sCw[w][row][fr]      = fmaxf(nrm - 2.f * acc0[reg] + pn_a, 0.f);
    sCw[w][row][16 + fr] = fmaxf(nrm - 2.f * acc1[reg] + pn_b, 0.f);
  }
  // DS pipe is in-order per wave: reads below see the writes above.

  // ---- Sinkhorn: problem = 8 CONTIGUOUS lanes, 4 p each ---------------------
  const int i = l >> 3;               // problem 0..7 within wave
  const int s = l & 7;                // p-slice: p in [4s, 4s+4)
  float c0[4], c1[4];
  {
    float4 v0 = *(const float4*)&sCw[w][i][4 * s];       // token costs
    float4 v1 = *(const float4*)&sCw[w][8 + i][4 * s];   // anchor costs
    c0[0] = v0.x; c0[1] = v0.y; c0[2] = v0.z; c0[3] = v0.w;
    c1[0] = v1.x; c1[1] = v1.y; c1[2] = v1.z; c1[3] = v1.w;
  }

  float W[4], dc[4];
  float sum0 = 0.f, mA = -1e30f, mB = -1e30f;
  #pragma unroll
  for (int r2 = 0; r2 < 4; ++r2) {
    float ka = -c0[r2] * C_SCALE, kb = -c1[r2] * C_SCALE;
    dc[r2] = c1[r2] - c0[r2];
    sum0 += c0[r2];
    mA = fmaxf(mA, ka);
    mB = fmaxf(mB, kb);
  }
  mA = dpp_max8(mA);
  mB = dpp_max8(mB);
  float sa = 0.f, sb = 0.f;
  #pragma unroll
  for (int r2 = 0; r2 < 4; ++r2) {
    float ka = -c0[r2] * C_SCALE, kb = -c1[r2] * C_SCALE;
    sa += EXP2F(ka - mA);
    sb += EXP2F(kb - mB);
    W[r2] = EXP2F(C_SCALE * dc[r2]);  // 2^(k0-k1)
  }
  sa   = dpp_sum8(sa);
  sb   = dpp_sum8(sb);
  sum0 = dpp_sum8(sum0);
  // iteration 1 (reference: lv=0): delta1 = lse2(k1) - lse2(k0)
  float delta = (mB + LOG2F(sb)) - (mA + LOG2F(sa));

  // iterations 2..50: fixed-point w/ geometric extrapolation + fp32 exit.
  float updPrev = delta;              // "update" from the d=0 start
  float rPrev   = -1.f;
  bool  live    = true;
  for (int it = 0; it < 49; ++it) {
    float s2 = EXP2F(delta);
    float T = 0.f;
    #pragma unroll
    for (int r2 = 0; r2 < 4; ++r2)
      T += RCPF(__builtin_fmaf(W[r2], s2, 1.0f));   // sigma_p
    T = dpp_sum8(T);                  // in (0,32), uniform over the 8 lanes
    float upd = LOG2F(T) - LOG2F(32.0f - T);
    float rr  = upd * RCPF(updPrev);  // observed contraction ratio
    bool small = fabsf(upd) <= 5e-7f;
    bool geo = live && !small && (it >= 3)
             && (rr > 0.001f) && (rr < 0.998f)
             && (fabsf(rr - rPrev) < 0.002f);
    float mrem = (float)(48 - it);    // fixed-point steps left after this one
    float jump = geo
        ? upd * rr * (1.0f - EXP2F(mrem * LOG2F(rr))) * RCPF(1.0f - rr)
        : 0.0f;
    if (live) delta += upd + jump;
    live = live && !small && !geo;
    rPrev = rr; updPrev = upd;
    if (__ballot(live) == 0ull) break;
  }

  // ---- final transport & outputs -------------------------------------------
  float s2 = EXP2F(delta), sv = 0.f;
  #pragma unroll
  for (int r2 = 0; r2 < 4; ++r2)
    sv += RCPF(__builtin_fmaf(W[r2], s2, 1.0f)) * dc[r2];
  sv = dpp_sum8(sv);
  if (s == 0) {
    int b = b0 + 8 * w + i;
    float ot  = (sum0 + sv) * 0.03125f;
    float val = RCPF(1.0f + EXP2F(LOG2E * 6.0f * (ot - 0.25f)));
    outVal[b * EDIM + e] = val;
    outOt [b * EDIM + e] = ot;
  }
}

extern "C" void kernel_launch(void* const* d_in, const int* in_sizes, int n_in,
                              void* d_out, int out_size, void* d_ws, size_t ws_size,
                              hipStream_t stream) {
  const float* tokens = (const float*)d_in[0];   // (8192, 8, 512) fp32
  const float* protos = (const float*)d_in[1];   // (8, 32, 512) fp32
  const int*   fidx   = (const int*)d_in[2];     // scalar
  float* out = (float*)d_out;                    // 65536 validity + 65536 ot

  __bf16* pbf   = (__bf16*)d_ws;                          // 256 KiB
  float*  pnorm = (float*)((char*)d_ws + 256 * 1024);     // 1 KiB

  prep_protos_kernel<<<64, 256, 0, stream>>>(protos, fidx, pbf, pnorm, out);
  dim3 grid(7 * (BDIM / BPB));                   // 1792 working blocks
  ot_noise_gate_kernel<<<grid, NTHR, 0, stream>>>(tokens, pbf, pnorm, fidx, out);
}

// Round 5
// 194.032 us; speedup vs baseline: 1.0649x; 1.0024x over previous
//
#include <hip/hip_runtime.h>
#include <hip/hip_bf16.h>

// OTNoiseGate: B=8192, E=8, D=512, P=32, eps=0.05, 50 Sinkhorn iters.
// R11 = R10 resubmitted unchanged (R10 bench was an infra failure:
// "MI355X container failed twice" — kernel never ran).
// R10 = R9 (prep-packed bf16 protos, global_load_lds staging, PFD=6,
// XCD-balanced 1792-block grid, DPP Sinkhorn + geometric extrapolation)
// + occupancy 3 -> 4 blocks/CU:
//  - sCw stride 36 -> 32 floats: LDS 41984 -> 40960 B = exactly 160K/4.
//    (one-time cost-tile LDS ops become mildly bank-conflicted; ~100s of
//    cycles once per wave, vs +33% waves for the latency-bound stream.)
//  - __launch_bounds__(256,4): VGPR cap 128 -> 4 waves/SIMD.

#define EXP2F(x) __builtin_amdgcn_exp2f(x)
#define LOG2F(x) __builtin_amdgcn_logf(x)   // v_log_f32 = log2
#define RCPF(x)  __builtin_amdgcn_rcpf(x)

typedef __bf16 bf16x8 __attribute__((ext_vector_type(8)));
typedef float  f32x4  __attribute__((ext_vector_type(4)));

#define BDIM 8192
#define EDIM 8
#define DDIM 512
#define PDIM 32
#define BPB  32             // problems per block (8 per wave x 4 waves)
#define NTHR 256
#define PFD  6              // prefetch depth (chunks in flight per lane)
#define C_SCALE 28.853900817779268f   // log2(e)/eps
#define LOG2E   1.4426950408889634f

#define GLOBAL_AS __attribute__((address_space(1)))
#define LDS_AS    __attribute__((address_space(3)))

__device__ __forceinline__ void gload_lds16(const void* g, void* l) {
  // dest: wave-uniform base + lane*16 (hardware-defined); src: per-lane addr
  __builtin_amdgcn_global_load_lds((GLOBAL_AS const void*)g,
                                   (LDS_AS void*)l, 16, 0, 0);
}

// ---- DPP cross-lane helpers: reduce within contiguous 8-lane groups ------
template<int CTRL>
__device__ __forceinline__ float dpp_mov(float x) {
  return __int_as_float(__builtin_amdgcn_update_dpp(
      0, __float_as_int(x), CTRL, 0xF, 0xF, true));
}
__device__ __forceinline__ float dpp_sum8(float x) {
  x += dpp_mov<0xB1>(x);    // quad_perm [1,0,3,2] : lane ^= 1
  x += dpp_mov<0x4E>(x);    // quad_perm [2,3,0,1] : lane ^= 2
  x += dpp_mov<0x141>(x);   // row_half_mirror     : other quad within 8
  return x;
}
__device__ __forceinline__ float dpp_max8(float x) {
  x = fmaxf(x, dpp_mov<0xB1>(x));
  x = fmaxf(x, dpp_mov<0x4E>(x));
  x = fmaxf(x, dpp_mov<0x141>(x));
  return x;
}

__device__ __forceinline__ bf16x8 cvt2(float4 a, float4 b) {
  bf16x8 r;
  r[0] = (__bf16)a.x; r[1] = (__bf16)a.y; r[2] = (__bf16)a.z; r[3] = (__bf16)a.w;
  r[4] = (__bf16)b.x; r[5] = (__bf16)b.y; r[6] = (__bf16)b.z; r[7] = (__bf16)b.w;
  return r;
}

// ---- prep: protos fp32 -> bf16 [e][oct][p][8] + norms[e*32+p],
//      and the masked-slice (e==fi) constant outputs.
// 16384 threads; wave = one (e,p), lane = oct (64 octs of 8 elems = 512).
__global__ __launch_bounds__(256)
void prep_protos_kernel(const float* __restrict__ protos,
                        const int*   __restrict__ fullIndexPtr,
                        __bf16* __restrict__ pbf,
                        float*  __restrict__ pnorm,
                        float*  __restrict__ out) {
  const int idx = blockIdx.x * 256 + threadIdx.x;   // 0..16383
  const int oct = idx & 63;
  const int ep  = idx >> 6;                          // e*32 + p
  const float4* src = (const float4*)(protos + (size_t)ep * DDIM) + oct * 2;
  float4 a = src[0], b = src[1];
  float pnp = a.x*a.x + a.y*a.y + a.z*a.z + a.w*a.w
            + b.x*b.x + b.y*b.y + b.z*b.z + b.w*b.w;
  const int e = ep >> 5;
  *(bf16x8*)&pbf[((size_t)e * 2048 + oct * 32 + (ep & 31)) * 8] = cvt2(a, b);
  #pragma unroll
  for (int d = 1; d < 64; d <<= 1) pnp += __shfl_xor(pnp, d);
  if (oct == 0) pnorm[ep] = pnp;

  // masked slice (e==fi): validity=1, ot=0 for all b
  const int fi = fullIndexPtr[0];
  if (idx < BDIM) {
    out[(size_t)idx * EDIM + fi] = 1.0f;                     // validity
    out[(size_t)BDIM * EDIM + (size_t)idx * EDIM + fi] = 0.0f; // ot_cost
  }
}

__global__ __launch_bounds__(NTHR, 4)    // 4 blocks/CU, VGPR cap 128
void ot_noise_gate_kernel(const float* __restrict__ tokens,
                          const __bf16* __restrict__ pbf,
                          const float*  __restrict__ pnorm,
                          const int*   __restrict__ fullIndexPtr,
                          float*       __restrict__ out) {
  const int fi = fullIndexPtr[0];
  // XCD-balanced decomposition: 1792 working blocks.
  const int u    = blockIdx.x;
  const int xcd  = u & 7;            // HW: XCD = blockIdx % 8 (round-robin)
  const int r    = u >> 3;           // 0..223
  const int cHi  = r / 7;            // 0..31
  const int eIdx = r - cHi * 7;      // 0..6
  const int chunk = cHi * 8 + xcd;   // same-chunk blocks share an XCD
  const int e    = eIdx + (eIdx >= fi ? 1 : 0);   // skip the masked slice
  const int b0   = chunk * BPB;
  float* outVal = out;                         // validity (B,E,1)
  float* outOt  = out + BDIM * EDIM;           // ot_cost  (B,E)

  __shared__ __align__(16) __bf16 sB[64 * PDIM * 8];  // [oct][p][8] = 32 KiB
  __shared__ __align__(16) float sCw[4][16][32];      // wave-private cost tiles

  const int t  = threadIdx.x;
  const int l  = t & 63;
  const int w  = t >> 6;              // wave 0..3 -> problems b0+8w .. +7
  const int fr = l & 15;              // fragment lane index (M-row / N-col)
  const int q4 = l >> 4;              // k-slice selector (0..3)

  // ---- A-fragment pointer: M-rows 0-7 tokens, 8-15 anchors ------------------
  const int bRow = b0 + 8 * w + (fr & 7);
  const int eSel = (fr < 8) ? e : fi;
  const float4* rp4 = (const float4*)(tokens + ((size_t)bRow * EDIM + eSel) * DDIM);

  // prefetch chunks 0..PFD-1 (in flight during proto staging + barrier drain)
  float4 buf[PFD][2];
  #pragma unroll
  for (int c = 0; c < PFD; ++c) {
    buf[c][0] = rp4[c * 8 + q4 * 2];
    buf[c][1] = rp4[c * 8 + q4 * 2 + 1];
  }

  // ---- stage protos[e] (pre-packed bf16) -> LDS via global_load_lds ---------
  // slots f = oct*32+p (16 B each); wave w covers f in [w*512, w*512+512),
  // 8 insts x 64 lanes x 16 B; dest is linear: base + lane*16.
  {
    const __bf16* pbfE = pbf + (size_t)e * 2048 * 8;
    #pragma unroll
    for (int j = 0; j < 8; ++j) {
      int f0 = w * 512 + j * 64;
      gload_lds16(pbfE + (size_t)(f0 + l) * 8, &sB[(size_t)f0 * 8]);
    }
  }
  // proto norms for this lane's two columns (tiny, L2-hot)
  float pn_a = pnorm[e * PDIM + fr];
  float pn_b = pnorm[e * PDIM + 16 + fr];
  __syncthreads();                    // the ONLY barrier (drains vmcnt)

  // ---- K-loop: 6-deep pipelined global A, LDS B, 2 MFMA/chunk ---------------
  f32x4 acc0 = (f32x4){0.f, 0.f, 0.f, 0.f};
  f32x4 acc1 = (f32x4){0.f, 0.f, 0.f, 0.f};
  float ss = 0.f;                     // partial ||row fr||^2 over this lane's k

  #pragma unroll
  for (int kc = 0; kc < 16; ++kc) {
    float4 ca0 = buf[kc % PFD][0];
    float4 ca1 = buf[kc % PFD][1];
    if (kc < 16 - PFD) {              // refill slot; lands PFD chunks ahead
      buf[kc % PFD][0] = rp4[(kc + PFD) * 8 + q4 * 2];
      buf[kc % PFD][1] = rp4[(kc + PFD) * 8 + q4 * 2 + 1];
    }
    ss += ca0.x*ca0.x + ca0.y*ca0.y + ca0.z*ca0.z + ca0.w*ca0.w
        + ca1.x*ca1.x + ca1.y*ca1.y + ca1.z*ca1.z + ca1.w*ca1.w;
    bf16x8 aF  = cvt2(ca0, ca1);
    bf16x8 bF0 = *(const bf16x8*)&sB[((kc * 4 + q4) * PDIM + fr) * 8];
    bf16x8 bF1 = *(const bf16x8*)&sB[((kc * 4 + q4) * PDIM + 16 + fr) * 8];
    acc0 = __builtin_amdgcn_mfma_f32_16x16x32_bf16(aF, bF0, acc0, 0, 0, 0);
    acc1 = __builtin_amdgcn_mfma_f32_16x16x32_bf16(aF, bF1, acc1, 0, 0, 0);
  }

  // ---- norms: reduce the 4 k-slices of each row -----------------------------
  ss += __shfl_xor(ss, 16);
  ss += __shfl_xor(ss, 32);           // lanes (fr,*) now hold ||row fr||^2

  // ---- epilogue: cost -> wave-private LDS tile ------------------------------
  #pragma unroll
  for (int reg = 0; reg < 4; ++reg) {
    int row = q4 * 4 + reg;           // C/D: row=(l>>4)*4+reg, col=fr
    float nrm = __shfl(ss, row);      // norm of M-row `row`
    sCw[w][row][fr]      = fmaxf(nrm - 2.f * acc0[reg] + pn_a, 0.f);
    sCw[w][row][16 + fr] = fmaxf(nrm - 2.f * acc1[reg] + pn_b, 0.f);
  }
  // DS pipe is in-order per wave: reads below see the writes above.

  // ---- Sinkhorn: problem = 8 CONTIGUOUS lanes, 4 p each ---------------------
  const int i = l >> 3;               // problem 0..7 within wave
  const int s = l & 7;                // p-slice: p in [4s, 4s+4)
  float c0[4], c1[4];
  {
    float4 v0 = *(const float4*)&sCw[w][i][4 * s];       // token costs
    float4 v1 = *(const float4*)&sCw[w][8 + i][4 * s];   // anchor costs
    c0[0] = v0.x; c0[1] = v0.y; c0[2] = v0.z; c0[3] = v0.w;
    c1[0] = v1.x; c1[1] = v1.y; c1[2] = v1.z; c1[3] = v1.w;
  }

  float W[4], dc[4];
  float sum0 = 0.f, mA = -1e30f, mB = -1e30f;
  #pragma unroll
  for (int r2 = 0; r2 < 4; ++r2) {
    float ka = -c0[r2] * C_SCALE, kb = -c1[r2] * C_SCALE;
    dc[r2] = c1[r2] - c0[r2];
    sum0 += c0[r2];
    mA = fmaxf(mA, ka);
    mB = fmaxf(mB, kb);
  }
  mA = dpp_max8(mA);
  mB = dpp_max8(mB);
  float sa = 0.f, sb = 0.f;
  #pragma unroll
  for (int r2 = 0; r2 < 4; ++r2) {
    float ka = -c0[r2] * C_SCALE, kb = -c1[r2] * C_SCALE;
    sa += EXP2F(ka - mA);
    sb += EXP2F(kb - mB);
    W[r2] = EXP2F(C_SCALE * dc[r2]);  // 2^(k0-k1)
  }
  sa   = dpp_sum8(sa);
  sb   = dpp_sum8(sb);
  sum0 = dpp_sum8(sum0);
  // iteration 1 (reference: lv=0): delta1 = lse2(k1) - lse2(k0)
  float delta = (mB + LOG2F(sb)) - (mA + LOG2F(sa));

  // iterations 2..50: fixed-point w/ geometric extrapolation + fp32 exit.
  float updPrev = delta;              // "update" from the d=0 start
  float rPrev   = -1.f;
  bool  live    = true;
  for (int it = 0; it < 49; ++it) {
    float s2 = EXP2F(delta);
    float T = 0.f;
    #pragma unroll
    for (int r2 = 0; r2 < 4; ++r2)
      T += RCPF(__builtin_fmaf(W[r2], s2, 1.0f));   // sigma_p
    T = dpp_sum8(T);                  // in (0,32), uniform over the 8 lanes
    float upd = LOG2F(T) - LOG2F(32.0f - T);
    float rr  = upd * RCPF(updPrev);  // observed contraction ratio
    bool small = fabsf(upd) <= 5e-7f;
    bool geo = live && !small && (it >= 3)
             && (rr > 0.001f) && (rr < 0.998f)
             && (fabsf(rr - rPrev) < 0.002f);
    float mrem = (float)(48 - it);    // fixed-point steps left after this one
    float jump = geo
        ? upd * rr * (1.0f - EXP2F(mrem * LOG2F(rr))) * RCPF(1.0f - rr)
        : 0.0f;
    if (live) delta += upd + jump;
    live = live && !small && !geo;
    rPrev = rr; updPrev = upd;
    if (__ballot(live) == 0ull) break;
  }

  // ---- final transport & outputs -------------------------------------------
  float s2 = EXP2F(delta), sv = 0.f;
  #pragma unroll
  for (int r2 = 0; r2 < 4; ++r2)
    sv += RCPF(__builtin_fmaf(W[r2], s2, 1.0f)) * dc[r2];
  sv = dpp_sum8(sv);
  if (s == 0) {
    int b = b0 + 8 * w + i;
    float ot  = (sum0 + sv) * 0.03125f;
    float val = RCPF(1.0f + EXP2F(LOG2E * 6.0f * (ot - 0.25f)));
    outVal[b * EDIM + e] = val;
    outOt [b * EDIM + e] = ot;
  }
}

extern "C" void kernel_launch(void* const* d_in, const int* in_sizes, int n_in,
                              void* d_out, int out_size, void* d_ws, size_t ws_size,
                              hipStream_t stream) {
  const float* tokens = (const float*)d_in[0];   // (8192, 8, 512) fp32
  const float* protos = (const float*)d_in[1];   // (8, 32, 512) fp32
  const int*   fidx   = (const int*)d_in[2];     // scalar
  float* out = (float*)d_out;                    // 65536 validity + 65536 ot

  __bf16* pbf   = (__bf16*)d_ws;                          // 256 KiB
  float*  pnorm = (float*)((char*)d_ws + 256 * 1024);     // 1 KiB

  prep_protos_kernel<<<64, 256, 0, stream>>>(protos, fidx, pbf, pnorm, out);
  dim3 grid(7 * (BDIM / BPB));                   // 1792 working blocks
  ot_noise_gate_kernel<<<grid, NTHR, 0, stream>>>(tokens, pbf, pnorm, fidx, out);
}